// Round 1
// baseline (166.613 us; speedup 1.0000x reference)
//
#include <hip/hip_runtime.h>
#include <hip/hip_bf16.h>

typedef __attribute__((ext_vector_type(8))) short short8;
typedef __attribute__((ext_vector_type(4))) float f32x4;
typedef __attribute__((ext_vector_type(2))) unsigned int u32x2;

__device__ __forceinline__ unsigned short f2bf(float x) {
    unsigned int u = __float_as_uint(x);
    unsigned int lsb = (u >> 16) & 1u;
    u += 0x7fffu + lsb;                    // round-to-nearest-even
    return (unsigned short)(u >> 16);
}

__device__ __forceinline__ float bf2f(unsigned int b16) {
    return __uint_as_float(b16 << 16);
}

__device__ __forceinline__ short8 pack8(f32x4 a, f32x4 b) {
    short8 r;
    r[0] = (short)f2bf(a.x); r[1] = (short)f2bf(a.y);
    r[2] = (short)f2bf(a.z); r[3] = (short)f2bf(a.w);
    r[4] = (short)f2bf(b.x); r[5] = (short)f2bf(b.y);
    r[6] = (short)f2bf(b.z); r[7] = (short)f2bf(b.w);
    return r;
}

// Standalone init (fallback path): out[n][c] = bias[c]
__global__ __launch_bounds__(256) void k_init(const float* __restrict__ bias,
                                              float* __restrict__ out, long total4) {
    long i4 = (long)blockIdx.x * 256 + threadIdx.x;
    if (i4 < total4) {
        const f32x4* b4 = (const f32x4*)bias;
        ((f32x4*)out)[i4] = b4[i4 & 15];
    }
}

// Fused: blocks [0,gblocks) compute G = (feat @ W.T) in bf16 via MFMA;
// blocks [gblocks, ...) broadcast bias into out.
// NOTE: out init must be a PLAIN store — NT store streamed it to HBM and made
// every later atomic flush RMW against HBM (R4: WRITE_SIZE doubled, +22 us).
__global__ __launch_bounds__(256) void k_setup(const float* __restrict__ feat,
                                               const float* __restrict__ W,
                                               const float* __restrict__ bias,
                                               unsigned short* __restrict__ G,
                                               float* __restrict__ out,
                                               int N, int gblocks) {
    if ((int)blockIdx.x >= gblocks) {
        long i4 = (long)(blockIdx.x - gblocks) * 256 + threadIdx.x;
        long total4 = (long)N * 16;            // N*64 floats / 4
        if (i4 < total4) {
            const f32x4* b4 = (const f32x4*)bias;
            ((f32x4*)out)[i4] = b4[i4 & 15];   // plain store: stay dirty in L2
        }
        return;
    }

    int wave = blockIdx.x * 4 + (threadIdx.x >> 6);
    int lane = threadIdx.x & 63;
    int m0 = wave * 16;
    if (m0 >= N) return;
    int n = lane & 15;
    int quad = lane >> 4;

    // B fragments: B[k][c0+n] = W[c0+n][k]; k = ks*32 + quad*8 + j
    short8 bf[4][2];
#pragma unroll
    for (int ct = 0; ct < 4; ++ct)
#pragma unroll
        for (int ks = 0; ks < 2; ++ks) {
            const f32x4* wp = (const f32x4*)(W + (size_t)(ct * 16 + n) * 64 + ks * 32 + quad * 8);
            f32x4 w0 = wp[0];
            f32x4 w1 = wp[1];
            bf[ct][ks] = pack8(w0, w1);
        }

    // A fragments: A[m0+n][k]  (NT load: feat read exactly once)
    int mrow = m0 + n; if (mrow >= N) mrow = N - 1;
    short8 af[2];
#pragma unroll
    for (int ks = 0; ks < 2; ++ks) {
        const f32x4* ap = (const f32x4*)(feat + (size_t)mrow * 64 + ks * 32 + quad * 8);
        f32x4 a0 = __builtin_nontemporal_load(ap);
        f32x4 a1 = __builtin_nontemporal_load(ap + 1);
        af[ks] = pack8(a0, a1);
    }

    f32x4 acc[4];
#pragma unroll
    for (int ct = 0; ct < 4; ++ct) {
        acc[ct] = (f32x4){0.f, 0.f, 0.f, 0.f};
#pragma unroll
        for (int ks = 0; ks < 2; ++ks)
            acc[ct] = __builtin_amdgcn_mfma_f32_16x16x32_bf16(af[ks], bf[ct][ks], acc[ct], 0, 0, 0);
    }

    // D layout: col = lane&15 (=n), row = quad*4 + reg. Plain stores: G is
    // re-read by k_spmm, keep it in L2/L3.
#pragma unroll
    for (int ct = 0; ct < 4; ++ct)
#pragma unroll
        for (int r = 0; r < 4; ++r) {
            int rowm = m0 + quad * 4 + r;
            if (rowm < N)
                G[(size_t)rowm * 64 + ct * 16 + n] = f2bf(acc[ct][r]);
        }
}

// SpMM: out[row] += val * G[col]. Sorted rows. 64 edges/wave.
// R9: WIDE GATHERS. Previous version issued one global_load_ushort (128 B)
// per edge and was capped at ~24G vmem-instructions/s (latency x per-CU
// instruction-queue occupancy), not bandwidth. Now 4 edges share one
// global_load_dwordx2: lane l serves edge 4k+(l>>4), features
// [4*(l&15), 4*(l&15)+4) -> 512 B/instruction, 4x fewer gather instructions
// at identical cache-line traffic. All 16 pack-loads per wave are issued
// up-front (no flush stores interleaved in the in-flight window), then
// consumed. Per-lane cols/vals come from ds_bpermute; row boundaries stay
// wave-uniform (rows sorted): a vector compare masks val to 0 for quarters
// belonging to a different row. Flush: shfl_xor(16)+shfl_xor(32) quarter
// reduce, then lanes 0-15 store f32x4 (interior rows, bias+acc plain store)
// or 4x atomicAdd (first/last rows possibly shared across waves).
__global__ __launch_bounds__(256) void k_spmm(const unsigned short* __restrict__ G,
                                              const int* __restrict__ erow,
                                              const int* __restrict__ ecol,
                                              const float* __restrict__ evalv,
                                              const float* __restrict__ bias,
                                              float* __restrict__ out, int E) {
    int wave = blockIdx.x * 4 + (threadIdx.x >> 6);
    int lane = threadIdx.x & 63;
    long base0 = (long)wave * 64;
    if (base0 >= E) return;

    int fb = lane & 15;          // feature block: features [4*fb, 4*fb+4)
    int q  = lane >> 4;          // quarter = edge slot within a 4-edge pack
    f32x4 b4 = ((const f32x4*)bias)[fb];

    float acc0 = 0.f, acc1 = 0.f, acc2 = 0.f, acc3 = 0.f;
    bool first = true;           // first flushed row may be shared w/ prev wave
    int cur;

    // flush current row: reduce quarters, then store/atomic from lanes 0-15
    auto flush = [&](bool atomic_path) {
        float t0 = acc0 + __shfl_xor(acc0, 16);
        float t1 = acc1 + __shfl_xor(acc1, 16);
        float t2 = acc2 + __shfl_xor(acc2, 16);
        float t3 = acc3 + __shfl_xor(acc3, 16);
        t0 += __shfl_xor(t0, 32);
        t1 += __shfl_xor(t1, 32);
        t2 += __shfl_xor(t2, 32);
        t3 += __shfl_xor(t3, 32);
        if (lane < 16) {
            float* p = out + ((size_t)(unsigned)cur << 6) + ((unsigned)fb << 2);
            if (atomic_path) {
                atomicAdd(p + 0, t0);
                atomicAdd(p + 1, t1);
                atomicAdd(p + 2, t2);
                atomicAdd(p + 3, t3);
            } else {
                f32x4 o = {b4.x + t0, b4.y + t1, b4.z + t2, b4.w + t3};
                *(f32x4*)p = o;
            }
        }
        acc0 = acc1 = acc2 = acc3 = 0.f;
    };

    if (base0 + 64 <= E) {
        // ---- fast path: full 64-edge segment ----
        long i0 = base0 + lane;
        int rv = __builtin_nontemporal_load(erow + i0);
        int cv = __builtin_nontemporal_load(ecol + i0);
        int vv = __builtin_nontemporal_load((const int*)evalv + i0);

        cur = __builtin_amdgcn_readlane(rv, 0);

        int vq4 = q << 2;                     // bpermute byte index base
        unsigned vfb8 = (unsigned)fb << 3;    // byte offset within G row

        // issue all 16 pack-gathers up front: maximal outstanding window,
        // no stores interleaved before the consume phase.
        u32x2 g[16];
#pragma unroll
        for (int k = 0; k < 16; ++k) {
            int c = __builtin_amdgcn_ds_bpermute(vq4 + 16 * k, cv);
            unsigned off = ((unsigned)c << 7) + vfb8;
            g[k] = *(const u32x2*)((const char*)G + off);
        }
        __builtin_amdgcn_sched_barrier(0);    // keep loads ahead of consume

#pragma unroll
        for (int k = 0; k < 16; ++k) {
            int r0 = __builtin_amdgcn_readlane(rv, 4 * k);
            int r3 = __builtin_amdgcn_readlane(rv, 4 * k + 3);
            float vs = __int_as_float(__builtin_amdgcn_ds_bpermute(vq4 + 16 * k, vv));
            float f0 = __uint_as_float(g[k].x << 16);
            float f1 = __uint_as_float(g[k].x & 0xffff0000u);
            float f2 = __uint_as_float(g[k].y << 16);
            float f3 = __uint_as_float(g[k].y & 0xffff0000u);

            if (r0 == r3) {
                // whole pack in one row (common: avg row length 16)
                if (r0 != cur) { flush(first); first = false; cur = r0; }
                acc0 = fmaf(vs, f0, acc0);
                acc1 = fmaf(vs, f1, acc1);
                acc2 = fmaf(vs, f2, acc2);
                acc3 = fmaf(vs, f3, acc3);
            } else {
                // row boundary inside pack: iterate distinct rows, vector-mask
                int rowsv = __builtin_amdgcn_ds_bpermute(vq4 + 16 * k, rv);
                int r1 = __builtin_amdgcn_readlane(rv, 4 * k + 1);
                int r2 = __builtin_amdgcn_readlane(rv, 4 * k + 2);
                int rr = r0;
                while (true) {
                    if (rr != cur) { flush(first); first = false; cur = rr; }
                    float vm = (rowsv == rr) ? vs : 0.f;
                    acc0 = fmaf(vm, f0, acc0);
                    acc1 = fmaf(vm, f1, acc1);
                    acc2 = fmaf(vm, f2, acc2);
                    acc3 = fmaf(vm, f3, acc3);
                    if (rr == r3) break;
                    rr = (r1 > rr) ? r1 : ((r2 > rr) ? r2 : r3);
                }
            }
        }
    } else {
        // ---- tail path: generic per-edge loop (same acc layout) ----
        cur = erow[base0];
        unsigned vfb8 = (unsigned)fb << 3;
        for (long e = base0; e < (long)E; ++e) {
            int r = erow[e];
            int c = ecol[e];
            float v = evalv[e];
            u32x2 gg = *(const u32x2*)((const char*)G + (((unsigned)c << 7) + vfb8));
            if (r != cur) { flush(first); first = false; cur = r; }
            float vm = (q == 0) ? v : 0.f;   // only quarter 0 accumulates
            acc0 = fmaf(vm, __uint_as_float(gg.x << 16), acc0);
            acc1 = fmaf(vm, __uint_as_float(gg.x & 0xffff0000u), acc1);
            acc2 = fmaf(vm, __uint_as_float(gg.y << 16), acc2);
            acc3 = fmaf(vm, __uint_as_float(gg.y & 0xffff0000u), acc3);
        }
    }

    // last row may be shared with the next wave -> always atomic
    flush(true);
}

// Fallback if ws too small: fused f32 gather + shfl transform at flush.
__global__ __launch_bounds__(256) void k_fused(const float* __restrict__ feat,
                                               const int* __restrict__ erow,
                                               const int* __restrict__ ecol,
                                               const float* __restrict__ evalv,
                                               const float* __restrict__ W,
                                               float* __restrict__ out,
                                               int E, int epw) {
    __shared__ float Wt[64 * 64];
    for (int i = threadIdx.x; i < 4096; i += 256) {
        int c = i >> 6, f = i & 63;
        Wt[f * 64 + c] = W[i];
    }
    __syncthreads();

    int wave = blockIdx.x * 4 + (threadIdx.x >> 6);
    int lane = threadIdx.x & 63;
    long e0 = (long)wave * epw;
    if (e0 >= E) return;
    long e1 = e0 + epw; if (e1 > E) e1 = E;

    int cur = erow[e0];
    float acc = 0.f;
    for (long e = e0; e < e1; ++e) {
        int r = erow[e];
        int c = ecol[e];
        float v = evalv[e];
        float g = feat[((size_t)c << 6) | lane];
        if (r != cur) {
            float res = 0.f;
#pragma unroll
            for (int f = 0; f < 64; ++f)
                res += __shfl(acc, f, 64) * Wt[f * 64 + lane];
            atomicAdd(out + ((size_t)cur << 6) + lane, res);
            acc = 0.f;
            cur = r;
        }
        acc += v * g;
    }
    {
        float res = 0.f;
#pragma unroll
        for (int f = 0; f < 64; ++f)
            res += __shfl(acc, f, 64) * Wt[f * 64 + lane];
        atomicAdd(out + ((size_t)cur << 6) + lane, res);
    }
}

extern "C" void kernel_launch(void* const* d_in, const int* in_sizes, int n_in,
                              void* d_out, int out_size, void* d_ws, size_t ws_size,
                              hipStream_t stream) {
    const float* feat  = (const float*)d_in[0];
    const int*   erow  = (const int*)d_in[1];
    const int*   ecol  = (const int*)d_in[2];
    const float* evalv = (const float*)d_in[3];
    const float* W     = (const float*)d_in[4];
    const float* bias  = (const float*)d_in[5];
    float* out = (float*)d_out;

    int N = in_sizes[0] / 64;
    int E = in_sizes[1];

    size_t need = (size_t)N * 64 * sizeof(unsigned short);
    if (ws_size >= need) {
        unsigned short* G = (unsigned short*)d_ws;
        int tiles = (N + 15) / 16;
        int gblocks = (tiles + 3) / 4;
        long total4 = (long)N * 16;
        int iblocks = (int)((total4 + 255) / 256);
        k_setup<<<gblocks + iblocks, 256, 0, stream>>>(feat, W, bias, G, out, N, gblocks);

        int nwaves = (E + 63) / 64;              // 64 edges/wave, 16 wide gathers
        int nblocks = (nwaves + 3) / 4;
        k_spmm<<<nblocks, 256, 0, stream>>>(G, erow, ecol, evalv, bias, out, E);
    } else {
        long total4 = (long)N * 16;
        k_init<<<(int)((total4 + 255) / 256), 256, 0, stream>>>(bias, out, total4);
        int epw = (E + 8191) / 8192;
        if (epw < 32) epw = 32;
        int nwaves = (E + epw - 1) / epw;
        int nblocks = (nwaves + 3) / 4;
        k_fused<<<nblocks, 256, 0, stream>>>(feat, erow, ecol, evalv, W, out, E, epw);
    }
}